// Round 1
// baseline (1698.175 us; speedup 1.0000x reference)
//
#include <hip/hip_runtime.h>
#include <math.h>

#define HID 64
#define KIN 512

// ---------------- encoder: h = x @ W_enc + b_enc ----------------
// block = 256 thr (4 waves). Each wave: 16 nodes, lane = column.
// acc[16] in regs; W staged in LDS in 128-k chunks; x via wave-broadcast float4.
__global__ __launch_bounds__(256) void enc_kernel(
    const float* __restrict__ x, const float* __restrict__ W,
    const float* __restrict__ b, float* __restrict__ h, int N) {
  __shared__ float Ws[128 * HID];  // 32 KB
  const int tid = threadIdx.x;
  const int col = tid & 63;
  const int wid = tid >> 6;
  const int nodeBase = blockIdx.x * 64 + wid * 16;
  const bool fullTile = (nodeBase + 16 <= N);
  const int nLocal = fullTile ? 16 : (nodeBase < N ? N - nodeBase : 0);

  float acc[16];
#pragma unroll
  for (int i = 0; i < 16; i++) acc[i] = 0.f;

  for (int kc = 0; kc < 4; kc++) {
    // cooperative load W[kc*128 .. +128][64] -> LDS (2048 float4 / 256 thr = 8 ea)
    const float4* Wg = (const float4*)(W + (size_t)kc * 128 * HID);
    float4* WsV = (float4*)Ws;
#pragma unroll
    for (int i = 0; i < 8; i++) WsV[tid + i * 256] = Wg[tid + i * 256];
    __syncthreads();

    const int kg0 = kc * 128;
    for (int k4 = 0; k4 < 32; k4++) {
      const int k = k4 * 4;
      const float w0 = Ws[(k + 0) * HID + col];
      const float w1 = Ws[(k + 1) * HID + col];
      const float w2 = Ws[(k + 2) * HID + col];
      const float w3 = Ws[(k + 3) * HID + col];
      const int kg = kg0 + k;
      if (fullTile) {
#pragma unroll
        for (int i = 0; i < 16; i++) {
          const float4 xv =
              *(const float4*)(x + (size_t)(nodeBase + i) * KIN + kg);
          acc[i] += xv.x * w0 + xv.y * w1 + xv.z * w2 + xv.w * w3;
        }
      } else {
        for (int i = 0; i < nLocal; i++) {
          const float4 xv =
              *(const float4*)(x + (size_t)(nodeBase + i) * KIN + kg);
          acc[i] += xv.x * w0 + xv.y * w1 + xv.z * w2 + xv.w * w3;
        }
      }
    }
    __syncthreads();
  }
  const float bc = b[col];
  for (int i = 0; i < nLocal; i++) {
    h[(size_t)(nodeBase + i) * HID + col] = acc[i] + bc;
  }
}

// ---------------- degree histogram ----------------
__global__ void hist_kernel(const int* __restrict__ dst, int* __restrict__ cnt,
                            int E, int N) {
  int e = blockIdx.x * blockDim.x + threadIdx.x;
  if (e < E) {
    int d = dst[e];
    if ((unsigned)d < (unsigned)N) atomicAdd(&cnt[d], 1);
  }
}

// ---------------- exclusive scan (single block) + inv_deg ----------------
__global__ __launch_bounds__(1024) void scan_kernel(
    const int* __restrict__ cnt, int* __restrict__ row_start,
    float* __restrict__ inv_deg, int N) {
  __shared__ int part[1024];
  const int tid = threadIdx.x;
  const int chunk = (N + 1023) / 1024;
  const int s0 = tid * chunk;
  const int s1 = min(s0 + chunk, N);
  int sum = 0;
  for (int i = s0; i < s1; i++) sum += cnt[i];
  part[tid] = sum;
  __syncthreads();
  for (int off = 1; off < 1024; off <<= 1) {
    int t = (tid >= off) ? part[tid - off] : 0;
    __syncthreads();
    part[tid] += t;
    __syncthreads();
  }
  int run = (tid > 0) ? part[tid - 1] : 0;  // exclusive prefix of this chunk
  for (int i = s0; i < s1; i++) {
    int c = cnt[i];
    row_start[i] = run;
    inv_deg[i] = (c > 0) ? 1.0f / (float)c : 0.0f;
    run += c;
  }
  if (tid == 1023) row_start[N] = part[1023];
}

// ---------------- bucket edges by dst (CSR) ----------------
__global__ void scatter_kernel(const int* __restrict__ src,
                               const int* __restrict__ dst,
                               const int* __restrict__ row_start,
                               int* __restrict__ cursor,
                               int* __restrict__ csr_src, int E, int N) {
  int e = blockIdx.x * blockDim.x + threadIdx.x;
  if (e < E) {
    int d = dst[e];
    if ((unsigned)d < (unsigned)N) {
      int pos = row_start[d] + atomicAdd(&cursor[d], 1);
      int s = src[e];
      if ((unsigned)s >= (unsigned)N) s = 0;  // crash guard; validation catches
      csr_src[pos] = s;
    }
  }
}

// ---------------- mean aggregation: agg[n] = inv_deg[n] * sum h[src] ----------------
// one wave per node, lane = feature column (coalesced 256B gathers)
__global__ __launch_bounds__(256) void agg_kernel(
    const float* __restrict__ h, const int* __restrict__ row_start,
    const int* __restrict__ csr_src, const float* __restrict__ inv_deg,
    float* __restrict__ agg, int N) {
  const int gw = (int)((blockIdx.x * (size_t)blockDim.x + threadIdx.x) >> 6);
  const int lane = threadIdx.x & 63;
  if (gw >= N) return;
  const int s = row_start[gw];
  const int e = row_start[gw + 1];
  float a0 = 0.f, a1 = 0.f;
  int i = s;
  for (; i + 1 < e; i += 2) {
    const int n0 = csr_src[i];
    const int n1 = csr_src[i + 1];
    a0 += h[(size_t)n0 * HID + lane];
    a1 += h[(size_t)n1 * HID + lane];
  }
  if (i < e) a0 += h[(size_t)csr_src[i] * HID + lane];
  agg[(size_t)gw * HID + lane] = (a0 + a1) * inv_deg[gw];
}

// ---------------- layer update: h = relu(h + agg@Wl + bl + h@Wr) ----------------
__global__ __launch_bounds__(256) void update_kernel(
    float* __restrict__ h, const float* __restrict__ agg,
    const float* __restrict__ Wl, const float* __restrict__ bl,
    const float* __restrict__ Wr, int N) {
  __shared__ float WlS[HID * HID];  // 16 KB
  __shared__ float WrS[HID * HID];  // 16 KB
  const int tid = threadIdx.x;
  const int col = tid & 63;
  const int wid = tid >> 6;
  {
    const float4* a = (const float4*)Wl;
    const float4* b2 = (const float4*)Wr;
    float4* sa = (float4*)WlS;
    float4* sb = (float4*)WrS;
#pragma unroll
    for (int i = 0; i < 4; i++) {
      sa[tid + i * 256] = a[tid + i * 256];
      sb[tid + i * 256] = b2[tid + i * 256];
    }
  }
  __syncthreads();

  const int nodeBase = blockIdx.x * 64 + wid * 16;
  const bool fullTile = (nodeBase + 16 <= N);
  const int nLocal = fullTile ? 16 : (nodeBase < N ? N - nodeBase : 0);

  float acc[16];
#pragma unroll
  for (int i = 0; i < 16; i++) acc[i] = 0.f;

  for (int k4 = 0; k4 < 16; k4++) {
    const int k = k4 * 4;
    const float l0 = WlS[(k + 0) * HID + col];
    const float l1 = WlS[(k + 1) * HID + col];
    const float l2 = WlS[(k + 2) * HID + col];
    const float l3 = WlS[(k + 3) * HID + col];
    const float r0 = WrS[(k + 0) * HID + col];
    const float r1 = WrS[(k + 1) * HID + col];
    const float r2 = WrS[(k + 2) * HID + col];
    const float r3 = WrS[(k + 3) * HID + col];
    if (fullTile) {
#pragma unroll
      for (int i = 0; i < 16; i++) {
        const size_t base = (size_t)(nodeBase + i) * HID + k;
        const float4 av = *(const float4*)(agg + base);
        const float4 hv = *(const float4*)(h + base);
        acc[i] += av.x * l0 + av.y * l1 + av.z * l2 + av.w * l3 +
                  hv.x * r0 + hv.y * r1 + hv.z * r2 + hv.w * r3;
      }
    } else {
      for (int i = 0; i < nLocal; i++) {
        const size_t base = (size_t)(nodeBase + i) * HID + k;
        const float4 av = *(const float4*)(agg + base);
        const float4 hv = *(const float4*)(h + base);
        acc[i] += av.x * l0 + av.y * l1 + av.z * l2 + av.w * l3 +
                  hv.x * r0 + hv.y * r1 + hv.z * r2 + hv.w * r3;
      }
    }
  }
  const float bc = bl[col];
  for (int i = 0; i < nLocal; i++) {
    const size_t idx = (size_t)(nodeBase + i) * HID + col;
    const float v = h[idx] + acc[i] + bc;
    h[idx] = v > 0.f ? v : 0.f;
  }
}

// ---------------- classifier: out = sigmoid(h @ W_cls + b_cls) ----------------
__global__ __launch_bounds__(256) void cls_kernel(
    const float* __restrict__ h, const float* __restrict__ Wc,
    const float* __restrict__ bc, float* __restrict__ out, int N) {
  const int gw = (int)((blockIdx.x * (size_t)blockDim.x + threadIdx.x) >> 6);
  const int lane = threadIdx.x & 63;
  if (gw >= N) return;
  float p = h[(size_t)gw * HID + lane] * Wc[lane];
#pragma unroll
  for (int off = 32; off > 0; off >>= 1) p += __shfl_down(p, off, 64);
  if (lane == 0) out[gw] = 1.0f / (1.0f + expf(-(p + bc[0])));
}

extern "C" void kernel_launch(void* const* d_in, const int* in_sizes, int n_in,
                              void* d_out, int out_size, void* d_ws,
                              size_t ws_size, hipStream_t stream) {
  const float* x = (const float*)d_in[0];
  const int* ei = (const int*)d_in[1];
  const float* W_enc = (const float*)d_in[2];
  const float* b_enc = (const float*)d_in[3];
  const float* Wl = (const float*)d_in[4];
  const float* bl = (const float*)d_in[5];
  const float* Wr = (const float*)d_in[6];
  const float* Wc = (const float*)d_in[7];
  const float* bc = (const float*)d_in[8];
  float* out = (float*)d_out;

  const int N = in_sizes[0] / KIN;
  const int E = in_sizes[1] / 2;
  const int* src = ei;
  const int* dst = ei + E;

  char* ws = (char*)d_ws;
  size_t off = 0;
  auto alloc = [&](size_t bytes) -> void* {
    void* p = ws + off;
    off += (bytes + 255) & ~(size_t)255;
    return p;
  };
  float* h = (float*)alloc((size_t)N * HID * sizeof(float));
  float* agg = (float*)alloc((size_t)N * HID * sizeof(float));
  int* cnt = (int*)alloc((size_t)N * sizeof(int));
  int* row_start = (int*)alloc((size_t)(N + 1) * sizeof(int));
  int* cursor = (int*)alloc((size_t)N * sizeof(int));
  float* inv_deg = (float*)alloc((size_t)N * sizeof(float));
  int* csr_src = (int*)alloc((size_t)E * sizeof(int));

  hipMemsetAsync(cnt, 0, (size_t)N * sizeof(int), stream);
  hipMemsetAsync(cursor, 0, (size_t)N * sizeof(int), stream);

  enc_kernel<<<(N + 63) / 64, 256, 0, stream>>>(x, W_enc, b_enc, h, N);
  hist_kernel<<<(E + 255) / 256, 256, 0, stream>>>(dst, cnt, E, N);
  scan_kernel<<<1, 1024, 0, stream>>>(cnt, row_start, inv_deg, N);
  scatter_kernel<<<(E + 255) / 256, 256, 0, stream>>>(src, dst, row_start,
                                                      cursor, csr_src, E, N);
  for (int l = 0; l < 3; l++) {
    agg_kernel<<<(N + 3) / 4, 256, 0, stream>>>(h, row_start, csr_src, inv_deg,
                                                agg, N);
    update_kernel<<<(N + 63) / 64, 256, 0, stream>>>(
        h, agg, Wl + (size_t)l * HID * HID, bl + (size_t)l * HID,
        Wr + (size_t)l * HID * HID, N);
  }
  cls_kernel<<<(N + 3) / 4, 256, 0, stream>>>(h, Wc, bc, out, N);
}

// Round 2
// 1186.882 us; speedup vs baseline: 1.4308x; 1.4308x over previous
//
#include <hip/hip_runtime.h>
#include <math.h>

#define HID 64
#define KIN 512

// ================= tiled fp32 GEMM building block =================
// block = 128 threads (2 waves). Block tile: 128 nodes x 64 cols.
// Wave = 64 nodes x 64 cols; lane (ng,cg) computes 8 nodes x 8 cols in regs.
// x staged transposed in LDS (xT[k][node], stride 132 keeps 16B align +
// breaks bank collisions); W chunk (32x64) staged row-major.
// Per k: 2 ds_read_b128 (x) + 2 ds_read_b128 (W) feed 64 FMAs -> 1 B/FMA.

// ---------------- encoder: h = x @ W_enc + b_enc ----------------
__global__ __launch_bounds__(128) void enc_kernel(
    const float* __restrict__ x, const float* __restrict__ W,
    const float* __restrict__ b, float* __restrict__ h, int N) {
  __shared__ float xs[32 * 132];  // 16.9 KB
  __shared__ float ws[32 * 64];   // 8 KB
  const int tid = threadIdx.x;
  const int lane = tid & 63;
  const int wid = tid >> 6;
  const int ng = lane >> 3;
  const int cg = lane & 7;
  const int blockBase = blockIdx.x * 128;

  float acc[8][8];
#pragma unroll
  for (int i = 0; i < 8; i++)
#pragma unroll
    for (int j = 0; j < 8; j++) acc[i][j] = 0.f;

  for (int kc = 0; kc < 16; kc++) {
    // stage x[blockBase..+128][kc*32..+32] transposed -> xs[k][n]
#pragma unroll
    for (int i = 0; i < 8; i++) {
      const int v = tid + i * 128;       // 0..1023
      const int nl = v >> 3;             // 0..127
      const int kq = v & 7;              // float4 index within 32 k
      const int gn = blockBase + nl;
      float4 xv = make_float4(0.f, 0.f, 0.f, 0.f);
      if (gn < N)
        xv = *(const float4*)(x + (size_t)gn * KIN + kc * 32 + kq * 4);
      xs[(kq * 4 + 0) * 132 + nl] = xv.x;
      xs[(kq * 4 + 1) * 132 + nl] = xv.y;
      xs[(kq * 4 + 2) * 132 + nl] = xv.z;
      xs[(kq * 4 + 3) * 132 + nl] = xv.w;
    }
    // stage W[kc*32..+32][64]
    {
      const float4* Wg = (const float4*)(W + (size_t)kc * 32 * HID);
      float4* wsv = (float4*)ws;
#pragma unroll
      for (int i = 0; i < 4; i++) wsv[tid + i * 128] = Wg[tid + i * 128];
    }
    __syncthreads();

    const int nb = wid * 64 + ng * 8;
#pragma unroll 4
    for (int k = 0; k < 32; k++) {
      const float4 a0 = *(const float4*)&xs[k * 132 + nb];
      const float4 a1 = *(const float4*)&xs[k * 132 + nb + 4];
      const float4 b0 = *(const float4*)&ws[k * HID + cg * 8];
      const float4 b1 = *(const float4*)&ws[k * HID + cg * 8 + 4];
      const float av[8] = {a0.x, a0.y, a0.z, a0.w, a1.x, a1.y, a1.z, a1.w};
      const float bv[8] = {b0.x, b0.y, b0.z, b0.w, b1.x, b1.y, b1.z, b1.w};
#pragma unroll
      for (int i = 0; i < 8; i++)
#pragma unroll
        for (int j = 0; j < 8; j++) acc[i][j] += av[i] * bv[j];
    }
    __syncthreads();
  }

  // epilogue: + bias, store
  float bj[8];
#pragma unroll
  for (int j = 0; j < 8; j++) bj[j] = b[cg * 8 + j];
  const int nb2 = blockBase + wid * 64 + ng * 8;
#pragma unroll
  for (int i = 0; i < 8; i++) {
    const int n = nb2 + i;
    if (n < N) {
      float4 o0, o1;
      o0.x = acc[i][0] + bj[0];
      o0.y = acc[i][1] + bj[1];
      o0.z = acc[i][2] + bj[2];
      o0.w = acc[i][3] + bj[3];
      o1.x = acc[i][4] + bj[4];
      o1.y = acc[i][5] + bj[5];
      o1.z = acc[i][6] + bj[6];
      o1.w = acc[i][7] + bj[7];
      *(float4*)(h + (size_t)n * HID + cg * 8) = o0;
      *(float4*)(h + (size_t)n * HID + cg * 8 + 4) = o1;
    }
  }
}

// ---------------- degree histogram ----------------
__global__ void hist_kernel(const int* __restrict__ dst, int* __restrict__ cnt,
                            int E, int N) {
  int e = blockIdx.x * blockDim.x + threadIdx.x;
  if (e < E) {
    int d = dst[e];
    if ((unsigned)d < (unsigned)N) atomicAdd(&cnt[d], 1);
  }
}

// ---------------- exclusive scan (single block) + inv_deg ----------------
__global__ __launch_bounds__(1024) void scan_kernel(
    const int* __restrict__ cnt, int* __restrict__ row_start,
    float* __restrict__ inv_deg, int N) {
  __shared__ int part[1024];
  const int tid = threadIdx.x;
  const int chunk = (N + 1023) / 1024;
  const int s0 = tid * chunk;
  const int s1 = min(s0 + chunk, N);
  int sum = 0;
  for (int i = s0; i < s1; i++) sum += cnt[i];
  part[tid] = sum;
  __syncthreads();
  for (int off = 1; off < 1024; off <<= 1) {
    int t = (tid >= off) ? part[tid - off] : 0;
    __syncthreads();
    part[tid] += t;
    __syncthreads();
  }
  int run = (tid > 0) ? part[tid - 1] : 0;
  for (int i = s0; i < s1; i++) {
    int c = cnt[i];
    row_start[i] = run;
    inv_deg[i] = (c > 0) ? 1.0f / (float)c : 0.0f;
    run += c;
  }
  if (tid == 1023) row_start[N] = part[1023];
}

// ---------------- bucket edges by dst (CSR) ----------------
__global__ void scatter_kernel(const int* __restrict__ src,
                               const int* __restrict__ dst,
                               const int* __restrict__ row_start,
                               int* __restrict__ cursor,
                               int* __restrict__ csr_src, int E, int N) {
  int e = blockIdx.x * blockDim.x + threadIdx.x;
  if (e < E) {
    int d = dst[e];
    if ((unsigned)d < (unsigned)N) {
      int pos = row_start[d] + atomicAdd(&cursor[d], 1);
      int s = src[e];
      if ((unsigned)s >= (unsigned)N) s = 0;
      csr_src[pos] = s;
    }
  }
}

// ---------------- mean aggregation ----------------
__global__ __launch_bounds__(256) void agg_kernel(
    const float* __restrict__ h, const int* __restrict__ row_start,
    const int* __restrict__ csr_src, const float* __restrict__ inv_deg,
    float* __restrict__ agg, int N) {
  const int gw = (int)((blockIdx.x * (size_t)blockDim.x + threadIdx.x) >> 6);
  const int lane = threadIdx.x & 63;
  if (gw >= N) return;
  const int s = row_start[gw];
  const int e = row_start[gw + 1];
  float a0 = 0.f, a1 = 0.f;
  int i = s;
  for (; i + 1 < e; i += 2) {
    const int n0 = csr_src[i];
    const int n1 = csr_src[i + 1];
    a0 += h[(size_t)n0 * HID + lane];
    a1 += h[(size_t)n1 * HID + lane];
  }
  if (i < e) a0 += h[(size_t)csr_src[i] * HID + lane];
  agg[(size_t)gw * HID + lane] = (a0 + a1) * inv_deg[gw];
}

// ---------------- layer update: h = relu(h + agg@Wl + bl + h@Wr) ----------------
// Same tiled structure as enc: K=128 as [agg | h] @ [Wl ; Wr], 4 phases of 32.
__global__ __launch_bounds__(128) void update_kernel(
    float* __restrict__ h, const float* __restrict__ agg,
    const float* __restrict__ Wl, const float* __restrict__ bl,
    const float* __restrict__ Wr, int N) {
  __shared__ float xs[32 * 132];
  __shared__ float ws[32 * 64];
  const int tid = threadIdx.x;
  const int lane = tid & 63;
  const int wid = tid >> 6;
  const int ng = lane >> 3;
  const int cg = lane & 7;
  const int blockBase = blockIdx.x * 128;

  float acc[8][8];
#pragma unroll
  for (int i = 0; i < 8; i++)
#pragma unroll
    for (int j = 0; j < 8; j++) acc[i][j] = 0.f;

  for (int ph = 0; ph < 4; ph++) {
    const float* __restrict__ src = (ph < 2) ? agg : h;
    const float* __restrict__ Wsrc = (ph < 2) ? Wl : Wr;
    const int ko = (ph & 1) * 32;
    // stage src rows transposed
#pragma unroll
    for (int i = 0; i < 8; i++) {
      const int v = tid + i * 128;
      const int nl = v >> 3;
      const int kq = v & 7;
      const int gn = blockBase + nl;
      float4 xv = make_float4(0.f, 0.f, 0.f, 0.f);
      if (gn < N)
        xv = *(const float4*)(src + (size_t)gn * HID + ko + kq * 4);
      xs[(kq * 4 + 0) * 132 + nl] = xv.x;
      xs[(kq * 4 + 1) * 132 + nl] = xv.y;
      xs[(kq * 4 + 2) * 132 + nl] = xv.z;
      xs[(kq * 4 + 3) * 132 + nl] = xv.w;
    }
    {
      const float4* Wg = (const float4*)(Wsrc + (size_t)ko * HID);
      float4* wsv = (float4*)ws;
#pragma unroll
      for (int i = 0; i < 4; i++) wsv[tid + i * 128] = Wg[tid + i * 128];
    }
    __syncthreads();

    const int nb = wid * 64 + ng * 8;
#pragma unroll 4
    for (int k = 0; k < 32; k++) {
      const float4 a0 = *(const float4*)&xs[k * 132 + nb];
      const float4 a1 = *(const float4*)&xs[k * 132 + nb + 4];
      const float4 b0 = *(const float4*)&ws[k * HID + cg * 8];
      const float4 b1 = *(const float4*)&ws[k * HID + cg * 8 + 4];
      const float av[8] = {a0.x, a0.y, a0.z, a0.w, a1.x, a1.y, a1.z, a1.w};
      const float bv[8] = {b0.x, b0.y, b0.z, b0.w, b1.x, b1.y, b1.z, b1.w};
#pragma unroll
      for (int i = 0; i < 8; i++)
#pragma unroll
        for (int j = 0; j < 8; j++) acc[i][j] += av[i] * bv[j];
    }
    __syncthreads();
  }

  // epilogue: residual + bias + relu; re-read h from global (L2-resident)
  float bj[8];
#pragma unroll
  for (int j = 0; j < 8; j++) bj[j] = bl[cg * 8 + j];
  const int nb2 = blockBase + wid * 64 + ng * 8;
#pragma unroll
  for (int i = 0; i < 8; i++) {
    const int n = nb2 + i;
    if (n < N) {
      const float4 h0 = *(const float4*)(h + (size_t)n * HID + cg * 8);
      const float4 h1 = *(const float4*)(h + (size_t)n * HID + cg * 8 + 4);
      float4 o0, o1;
      o0.x = h0.x + acc[i][0] + bj[0];
      o0.y = h0.y + acc[i][1] + bj[1];
      o0.z = h0.z + acc[i][2] + bj[2];
      o0.w = h0.w + acc[i][3] + bj[3];
      o1.x = h1.x + acc[i][4] + bj[4];
      o1.y = h1.y + acc[i][5] + bj[5];
      o1.z = h1.z + acc[i][6] + bj[6];
      o1.w = h1.w + acc[i][7] + bj[7];
      o0.x = o0.x > 0.f ? o0.x : 0.f;
      o0.y = o0.y > 0.f ? o0.y : 0.f;
      o0.z = o0.z > 0.f ? o0.z : 0.f;
      o0.w = o0.w > 0.f ? o0.w : 0.f;
      o1.x = o1.x > 0.f ? o1.x : 0.f;
      o1.y = o1.y > 0.f ? o1.y : 0.f;
      o1.z = o1.z > 0.f ? o1.z : 0.f;
      o1.w = o1.w > 0.f ? o1.w : 0.f;
      *(float4*)(h + (size_t)n * HID + cg * 8) = o0;
      *(float4*)(h + (size_t)n * HID + cg * 8 + 4) = o1;
    }
  }
}

// ---------------- classifier ----------------
__global__ __launch_bounds__(256) void cls_kernel(
    const float* __restrict__ h, const float* __restrict__ Wc,
    const float* __restrict__ bc, float* __restrict__ out, int N) {
  const int gw = (int)((blockIdx.x * (size_t)blockDim.x + threadIdx.x) >> 6);
  const int lane = threadIdx.x & 63;
  if (gw >= N) return;
  float p = h[(size_t)gw * HID + lane] * Wc[lane];
#pragma unroll
  for (int off = 32; off > 0; off >>= 1) p += __shfl_down(p, off, 64);
  if (lane == 0) out[gw] = 1.0f / (1.0f + expf(-(p + bc[0])));
}

extern "C" void kernel_launch(void* const* d_in, const int* in_sizes, int n_in,
                              void* d_out, int out_size, void* d_ws,
                              size_t ws_size, hipStream_t stream) {
  const float* x = (const float*)d_in[0];
  const int* ei = (const int*)d_in[1];
  const float* W_enc = (const float*)d_in[2];
  const float* b_enc = (const float*)d_in[3];
  const float* Wl = (const float*)d_in[4];
  const float* bl = (const float*)d_in[5];
  const float* Wr = (const float*)d_in[6];
  const float* Wc = (const float*)d_in[7];
  const float* bc = (const float*)d_in[8];
  float* out = (float*)d_out;

  const int N = in_sizes[0] / KIN;
  const int E = in_sizes[1] / 2;
  const int* src = ei;
  const int* dst = ei + E;

  char* ws = (char*)d_ws;
  size_t off = 0;
  auto alloc = [&](size_t bytes) -> void* {
    void* p = ws + off;
    off += (bytes + 255) & ~(size_t)255;
    return p;
  };
  float* h = (float*)alloc((size_t)N * HID * sizeof(float));
  float* agg = (float*)alloc((size_t)N * HID * sizeof(float));
  int* cnt = (int*)alloc((size_t)N * sizeof(int));
  int* row_start = (int*)alloc((size_t)(N + 1) * sizeof(int));
  int* cursor = (int*)alloc((size_t)N * sizeof(int));
  float* inv_deg = (float*)alloc((size_t)N * sizeof(float));
  int* csr_src = (int*)alloc((size_t)E * sizeof(int));

  hipMemsetAsync(cnt, 0, (size_t)N * sizeof(int), stream);
  hipMemsetAsync(cursor, 0, (size_t)N * sizeof(int), stream);

  enc_kernel<<<(N + 127) / 128, 128, 0, stream>>>(x, W_enc, b_enc, h, N);
  hist_kernel<<<(E + 255) / 256, 256, 0, stream>>>(dst, cnt, E, N);
  scan_kernel<<<1, 1024, 0, stream>>>(cnt, row_start, inv_deg, N);
  scatter_kernel<<<(E + 255) / 256, 256, 0, stream>>>(src, dst, row_start,
                                                      cursor, csr_src, E, N);
  for (int l = 0; l < 3; l++) {
    agg_kernel<<<(N + 3) / 4, 256, 0, stream>>>(h, row_start, csr_src, inv_deg,
                                                agg, N);
    update_kernel<<<(N + 127) / 128, 128, 0, stream>>>(
        h, agg, Wl + (size_t)l * HID * HID, bl + (size_t)l * HID,
        Wr + (size_t)l * HID * HID, N);
  }
  cls_kernel<<<(N + 3) / 4, 256, 0, stream>>>(h, Wc, bc, out, N);
}

// Round 3
// 886.877 us; speedup vs baseline: 1.9148x; 1.3383x over previous
//
#include <hip/hip_runtime.h>
#include <math.h>

#define HID 64
#define KIN 512

// ---------------- encoder: h = x @ W_enc + b_enc ----------------
// block = 128 thr (2 waves), tile 128 nodes x 64 cols, 8x8 per lane.
__global__ __launch_bounds__(128) void enc_kernel(
    const float* __restrict__ x, const float* __restrict__ W,
    const float* __restrict__ b, float* __restrict__ h, int N) {
  __shared__ float xs[32 * 132];  // 16.9 KB
  __shared__ float ws[32 * 64];   // 8 KB
  const int tid = threadIdx.x;
  const int lane = tid & 63;
  const int wid = tid >> 6;
  const int ng = lane >> 3;
  const int cg = lane & 7;
  const int blockBase = blockIdx.x * 128;

  float acc[8][8];
#pragma unroll
  for (int i = 0; i < 8; i++)
#pragma unroll
    for (int j = 0; j < 8; j++) acc[i][j] = 0.f;

  for (int kc = 0; kc < 16; kc++) {
#pragma unroll
    for (int i = 0; i < 8; i++) {
      const int v = tid + i * 128;
      const int nl = v >> 3;
      const int kq = v & 7;
      const int gn = blockBase + nl;
      float4 xv = make_float4(0.f, 0.f, 0.f, 0.f);
      if (gn < N)
        xv = *(const float4*)(x + (size_t)gn * KIN + kc * 32 + kq * 4);
      xs[(kq * 4 + 0) * 132 + nl] = xv.x;
      xs[(kq * 4 + 1) * 132 + nl] = xv.y;
      xs[(kq * 4 + 2) * 132 + nl] = xv.z;
      xs[(kq * 4 + 3) * 132 + nl] = xv.w;
    }
    {
      const float4* Wg = (const float4*)(W + (size_t)kc * 32 * HID);
      float4* wsv = (float4*)ws;
#pragma unroll
      for (int i = 0; i < 4; i++) wsv[tid + i * 128] = Wg[tid + i * 128];
    }
    __syncthreads();

    const int nb = wid * 64 + ng * 8;
#pragma unroll 4
    for (int k = 0; k < 32; k++) {
      const float4 a0 = *(const float4*)&xs[k * 132 + nb];
      const float4 a1 = *(const float4*)&xs[k * 132 + nb + 4];
      const float4 b0 = *(const float4*)&ws[k * HID + cg * 8];
      const float4 b1 = *(const float4*)&ws[k * HID + cg * 8 + 4];
      const float av[8] = {a0.x, a0.y, a0.z, a0.w, a1.x, a1.y, a1.z, a1.w};
      const float bv[8] = {b0.x, b0.y, b0.z, b0.w, b1.x, b1.y, b1.z, b1.w};
#pragma unroll
      for (int i = 0; i < 8; i++)
#pragma unroll
        for (int j = 0; j < 8; j++) acc[i][j] += av[i] * bv[j];
    }
    __syncthreads();
  }

  float bj[8];
#pragma unroll
  for (int j = 0; j < 8; j++) bj[j] = b[cg * 8 + j];
  const int nb2 = blockBase + wid * 64 + ng * 8;
#pragma unroll
  for (int i = 0; i < 8; i++) {
    const int n = nb2 + i;
    if (n < N) {
      float4 o0, o1;
      o0.x = acc[i][0] + bj[0];
      o0.y = acc[i][1] + bj[1];
      o0.z = acc[i][2] + bj[2];
      o0.w = acc[i][3] + bj[3];
      o1.x = acc[i][4] + bj[4];
      o1.y = acc[i][5] + bj[5];
      o1.z = acc[i][6] + bj[6];
      o1.w = acc[i][7] + bj[7];
      *(float4*)(h + (size_t)n * HID + cg * 8) = o0;
      *(float4*)(h + (size_t)n * HID + cg * 8 + 4) = o1;
    }
  }
}

// ---------------- degree histogram ----------------
__global__ void hist_kernel(const int* __restrict__ dst, int* __restrict__ cnt,
                            int E, int N) {
  int e = blockIdx.x * blockDim.x + threadIdx.x;
  if (e < E) {
    int d = dst[e];
    if ((unsigned)d < (unsigned)N) atomicAdd(&cnt[d], 1);
  }
}

// ---------------- parallel scan: phase A (block sums) ----------------
__global__ __launch_bounds__(1024) void scanA_kernel(
    const int* __restrict__ cnt, int* __restrict__ block_sums, int N) {
  __shared__ int red[1024];
  const int tid = threadIdx.x;
  const int i = blockIdx.x * 1024 + tid;
  red[tid] = (i < N) ? cnt[i] : 0;
  __syncthreads();
  for (int off = 512; off > 0; off >>= 1) {
    if (tid < off) red[tid] += red[tid + off];
    __syncthreads();
  }
  if (tid == 0) block_sums[blockIdx.x] = red[0];
}

// ---------------- phase B: scan block sums (single block) ----------------
__global__ __launch_bounds__(128) void scanB_kernel(
    int* __restrict__ block_sums, int* __restrict__ row_start, int nblk,
    int N) {
  __shared__ int part[128];
  const int tid = threadIdx.x;
  part[tid] = (tid < nblk) ? block_sums[tid] : 0;
  __syncthreads();
  for (int off = 1; off < 128; off <<= 1) {
    int t = (tid >= off) ? part[tid - off] : 0;
    __syncthreads();
    part[tid] += t;
    __syncthreads();
  }
  if (tid < nblk) block_sums[tid] = (tid > 0) ? part[tid - 1] : 0;  // exclusive
  if (tid == 127) row_start[N] = part[127];
}

// ---------------- phase C: local scan + apply offset ----------------
__global__ __launch_bounds__(1024) void scanC_kernel(
    const int* __restrict__ cnt, const int* __restrict__ block_sums,
    int* __restrict__ row_start, float* __restrict__ inv_deg, int N) {
  __shared__ int part[1024];
  const int tid = threadIdx.x;
  const int i = blockIdx.x * 1024 + tid;
  const int v = (i < N) ? cnt[i] : 0;
  part[tid] = v;
  __syncthreads();
  for (int off = 1; off < 1024; off <<= 1) {
    int t = (tid >= off) ? part[tid - off] : 0;
    __syncthreads();
    part[tid] += t;
    __syncthreads();
  }
  if (i < N) {
    row_start[i] = block_sums[blockIdx.x] + part[tid] - v;  // exclusive
    inv_deg[i] = (v > 0) ? 1.0f / (float)v : 0.0f;
  }
}

// ---------------- bucket edges by dst (CSR) ----------------
__global__ void scatter_kernel(const int* __restrict__ src,
                               const int* __restrict__ dst,
                               const int* __restrict__ row_start,
                               int* __restrict__ cursor,
                               int* __restrict__ csr_src, int E, int N) {
  int e = blockIdx.x * blockDim.x + threadIdx.x;
  if (e < E) {
    int d = dst[e];
    if ((unsigned)d < (unsigned)N) {
      int pos = row_start[d] + atomicAdd(&cursor[d], 1);
      int s = src[e];
      if ((unsigned)s >= (unsigned)N) s = 0;
      csr_src[pos] = s;
    }
  }
}

// ---------------- mean aggregation ----------------
// one wave per node; lane = (edge-subgroup 0..3, float4-idx 0..15).
// Each iteration gathers 4 edges x 256B with float4 loads (4x MLP of R2).
__global__ __launch_bounds__(256) void agg_kernel(
    const float* __restrict__ h, const int* __restrict__ row_start,
    const int* __restrict__ csr_src, const float* __restrict__ inv_deg,
    float* __restrict__ agg, int N) {
  const int gw = (int)((blockIdx.x * (size_t)blockDim.x + threadIdx.x) >> 6);
  const int lane = threadIdx.x & 63;
  if (gw >= N) return;
  const int sub = lane >> 4;   // 0..3
  const int fq = lane & 15;    // float4 index
  const int s = row_start[gw];
  const int e = row_start[gw + 1];
  float4 acc = make_float4(0.f, 0.f, 0.f, 0.f);
  for (int i = s; i < e; i += 4) {
    const int ei = i + sub;
    if (ei < e) {
      const int n = csr_src[ei];
      const float4 v = *(const float4*)(h + (size_t)n * HID + fq * 4);
      acc.x += v.x;
      acc.y += v.y;
      acc.z += v.z;
      acc.w += v.w;
    }
  }
  // reduce across the 4 subgroups (stride 32, then 16)
#pragma unroll
  for (int off = 32; off >= 16; off >>= 1) {
    acc.x += __shfl_down(acc.x, off, 64);
    acc.y += __shfl_down(acc.y, off, 64);
    acc.z += __shfl_down(acc.z, off, 64);
    acc.w += __shfl_down(acc.w, off, 64);
  }
  if (sub == 0) {
    const float id = inv_deg[gw];
    float4 o;
    o.x = acc.x * id;
    o.y = acc.y * id;
    o.z = acc.z * id;
    o.w = acc.w * id;
    *(float4*)(agg + (size_t)gw * HID + fq * 4) = o;
  }
}

// ---------------- layer update: h = relu(h + agg@Wl + bl + h@Wr) ----------------
__global__ __launch_bounds__(128) void update_kernel(
    float* __restrict__ h, const float* __restrict__ agg,
    const float* __restrict__ Wl, const float* __restrict__ bl,
    const float* __restrict__ Wr, int N) {
  __shared__ float xs[32 * 132];
  __shared__ float ws[32 * 64];
  const int tid = threadIdx.x;
  const int lane = tid & 63;
  const int wid = tid >> 6;
  const int ng = lane >> 3;
  const int cg = lane & 7;
  const int blockBase = blockIdx.x * 128;

  float acc[8][8];
#pragma unroll
  for (int i = 0; i < 8; i++)
#pragma unroll
    for (int j = 0; j < 8; j++) acc[i][j] = 0.f;

  for (int ph = 0; ph < 4; ph++) {
    const float* __restrict__ src = (ph < 2) ? agg : h;
    const float* __restrict__ Wsrc = (ph < 2) ? Wl : Wr;
    const int ko = (ph & 1) * 32;
#pragma unroll
    for (int i = 0; i < 8; i++) {
      const int v = tid + i * 128;
      const int nl = v >> 3;
      const int kq = v & 7;
      const int gn = blockBase + nl;
      float4 xv = make_float4(0.f, 0.f, 0.f, 0.f);
      if (gn < N)
        xv = *(const float4*)(src + (size_t)gn * HID + ko + kq * 4);
      xs[(kq * 4 + 0) * 132 + nl] = xv.x;
      xs[(kq * 4 + 1) * 132 + nl] = xv.y;
      xs[(kq * 4 + 2) * 132 + nl] = xv.z;
      xs[(kq * 4 + 3) * 132 + nl] = xv.w;
    }
    {
      const float4* Wg = (const float4*)(Wsrc + (size_t)ko * HID);
      float4* wsv = (float4*)ws;
#pragma unroll
      for (int i = 0; i < 4; i++) wsv[tid + i * 128] = Wg[tid + i * 128];
    }
    __syncthreads();

    const int nb = wid * 64 + ng * 8;
#pragma unroll 4
    for (int k = 0; k < 32; k++) {
      const float4 a0 = *(const float4*)&xs[k * 132 + nb];
      const float4 a1 = *(const float4*)&xs[k * 132 + nb + 4];
      const float4 b0 = *(const float4*)&ws[k * HID + cg * 8];
      const float4 b1 = *(const float4*)&ws[k * HID + cg * 8 + 4];
      const float av[8] = {a0.x, a0.y, a0.z, a0.w, a1.x, a1.y, a1.z, a1.w};
      const float bv[8] = {b0.x, b0.y, b0.z, b0.w, b1.x, b1.y, b1.z, b1.w};
#pragma unroll
      for (int i = 0; i < 8; i++)
#pragma unroll
        for (int j = 0; j < 8; j++) acc[i][j] += av[i] * bv[j];
    }
    __syncthreads();
  }

  float bj[8];
#pragma unroll
  for (int j = 0; j < 8; j++) bj[j] = bl[cg * 8 + j];
  const int nb2 = blockBase + wid * 64 + ng * 8;
#pragma unroll
  for (int i = 0; i < 8; i++) {
    const int n = nb2 + i;
    if (n < N) {
      const float4 h0 = *(const float4*)(h + (size_t)n * HID + cg * 8);
      const float4 h1 = *(const float4*)(h + (size_t)n * HID + cg * 8 + 4);
      float4 o0, o1;
      o0.x = h0.x + acc[i][0] + bj[0];
      o0.y = h0.y + acc[i][1] + bj[1];
      o0.z = h0.z + acc[i][2] + bj[2];
      o0.w = h0.w + acc[i][3] + bj[3];
      o1.x = h1.x + acc[i][4] + bj[4];
      o1.y = h1.y + acc[i][5] + bj[5];
      o1.z = h1.z + acc[i][6] + bj[6];
      o1.w = h1.w + acc[i][7] + bj[7];
      o0.x = o0.x > 0.f ? o0.x : 0.f;
      o0.y = o0.y > 0.f ? o0.y : 0.f;
      o0.z = o0.z > 0.f ? o0.z : 0.f;
      o0.w = o0.w > 0.f ? o0.w : 0.f;
      o1.x = o1.x > 0.f ? o1.x : 0.f;
      o1.y = o1.y > 0.f ? o1.y : 0.f;
      o1.z = o1.z > 0.f ? o1.z : 0.f;
      o1.w = o1.w > 0.f ? o1.w : 0.f;
      *(float4*)(h + (size_t)n * HID + cg * 8) = o0;
      *(float4*)(h + (size_t)n * HID + cg * 8 + 4) = o1;
    }
  }
}

// ---------------- classifier ----------------
__global__ __launch_bounds__(256) void cls_kernel(
    const float* __restrict__ h, const float* __restrict__ Wc,
    const float* __restrict__ bc, float* __restrict__ out, int N) {
  const int gw = (int)((blockIdx.x * (size_t)blockDim.x + threadIdx.x) >> 6);
  const int lane = threadIdx.x & 63;
  if (gw >= N) return;
  float p = h[(size_t)gw * HID + lane] * Wc[lane];
#pragma unroll
  for (int off = 32; off > 0; off >>= 1) p += __shfl_down(p, off, 64);
  if (lane == 0) out[gw] = 1.0f / (1.0f + expf(-(p + bc[0])));
}

extern "C" void kernel_launch(void* const* d_in, const int* in_sizes, int n_in,
                              void* d_out, int out_size, void* d_ws,
                              size_t ws_size, hipStream_t stream) {
  const float* x = (const float*)d_in[0];
  const int* ei = (const int*)d_in[1];
  const float* W_enc = (const float*)d_in[2];
  const float* b_enc = (const float*)d_in[3];
  const float* Wl = (const float*)d_in[4];
  const float* bl = (const float*)d_in[5];
  const float* Wr = (const float*)d_in[6];
  const float* Wc = (const float*)d_in[7];
  const float* bc = (const float*)d_in[8];
  float* out = (float*)d_out;

  const int N = in_sizes[0] / KIN;
  const int E = in_sizes[1] / 2;
  const int* src = ei;
  const int* dst = ei + E;

  char* ws = (char*)d_ws;
  size_t off = 0;
  auto alloc = [&](size_t bytes) -> void* {
    void* p = ws + off;
    off += (bytes + 255) & ~(size_t)255;
    return p;
  };
  float* h = (float*)alloc((size_t)N * HID * sizeof(float));
  float* agg = (float*)alloc((size_t)N * HID * sizeof(float));
  int* cnt = (int*)alloc((size_t)N * sizeof(int));
  int* row_start = (int*)alloc((size_t)(N + 1) * sizeof(int));
  int* cursor = (int*)alloc((size_t)N * sizeof(int));
  float* inv_deg = (float*)alloc((size_t)N * sizeof(float));
  int* csr_src = (int*)alloc((size_t)E * sizeof(int));
  const int nblk = (N + 1023) / 1024;
  int* block_sums = (int*)alloc((size_t)nblk * sizeof(int));

  hipMemsetAsync(cnt, 0, (size_t)N * sizeof(int), stream);
  hipMemsetAsync(cursor, 0, (size_t)N * sizeof(int), stream);

  enc_kernel<<<(N + 127) / 128, 128, 0, stream>>>(x, W_enc, b_enc, h, N);
  hist_kernel<<<(E + 255) / 256, 256, 0, stream>>>(dst, cnt, E, N);
  scanA_kernel<<<nblk, 1024, 0, stream>>>(cnt, block_sums, N);
  scanB_kernel<<<1, 128, 0, stream>>>(block_sums, row_start, nblk, N);
  scanC_kernel<<<nblk, 1024, 0, stream>>>(cnt, block_sums, row_start, inv_deg,
                                          N);
  scatter_kernel<<<(E + 255) / 256, 256, 0, stream>>>(src, dst, row_start,
                                                      cursor, csr_src, E, N);
  for (int l = 0; l < 3; l++) {
    agg_kernel<<<(N + 3) / 4, 256, 0, stream>>>(h, row_start, csr_src, inv_deg,
                                                agg, N);
    update_kernel<<<(N + 127) / 128, 128, 0, stream>>>(
        h, agg, Wl + (size_t)l * HID * HID, bl + (size_t)l * HID,
        Wr + (size_t)l * HID * HID, N);
  }
  cls_kernel<<<(N + 3) / 4, 256, 0, stream>>>(h, Wc, bc, out, N);
}